// Round 3
// baseline (293.436 us; speedup 1.0000x reference)
//
#include <hip/hip_runtime.h>
#include <math.h>
#include <limits.h>

#define kB 4
#define kC 8
#define kH 384
#define kW 384
#define kCH (kC * kH)   // 3072
#define kIN (2 * kCH)   // 6144
#define kNC 18
#define kMID (kW / 2)
#define NCHUNK 64
#define ROWS (kCH / NCHUNK)  // 48

#define E18(M) M(0) M(1) M(2) M(3) M(4) M(5) M(6) M(7) M(8) M(9) M(10) M(11) M(12) M(13) M(14) M(15) M(16) M(17)

// --------------------------------------------------------------------------
// K0: zero Pq|Pa (contiguous 2*B*W*18 floats) — ws is poisoned each call.
// --------------------------------------------------------------------------
__global__ __launch_bounds__(256)
void zero_kernel(float* __restrict__ P) {
    int i = blockIdx.x * 256 + threadIdx.x;
    if (i < 2 * kB * kW * kNC) P[i] = 0.0f;
}

// --------------------------------------------------------------------------
// K1: row-chunked projection. Grid (NCHUNK, B), 256 threads.
// waves 0-2: band columns of `acquired` (coalesced, each line fetched once).
// wave 3:    scattered acquiring columns of `acquiring`.
// Accumulate into Pq/Pa with HW fp32 atomics.
// --------------------------------------------------------------------------
__global__ __launch_bounds__(256)
void proj_kernel(const float* __restrict__ acquired,
                 const float* __restrict__ acquiring,
                 const float* __restrict__ am,
                 const float* __restrict__ qm,
                 const float* __restrict__ W1,
                 float* __restrict__ Pq, float* __restrict__ Pa) {
    int chunk = blockIdx.x, b = blockIdx.y, tid = threadIdx.x;
    int i0 = chunk * ROWS;

    // faithful left/right from acquired_mask (argmax(<1), 0 if none)
    __shared__ int sL[256], sR[256];
    int candR = INT_MAX, candL = INT_MAX;
    for (int i = tid; i < kW - kMID; i += 256)
        if (am[b * kW + kMID + i] < 1.0f) candR = min(candR, i);
    for (int i = tid; i < kMID; i += 256)
        if (am[b * kW + (kMID - 1 - i)] < 1.0f) candL = min(candL, i);
    sL[tid] = candL; sR[tid] = candR;
    __syncthreads();
    for (int s = 128; s > 0; s >>= 1) {
        if (tid < s) {
            sL[tid] = min(sL[tid], sL[tid + s]);
            sR[tid] = min(sR[tid], sR[tid + s]);
        }
        __syncthreads();
    }
    int left  = ((sL[0] == INT_MAX) ? 0 : sL[0]) + 1;
    int right = kMID + ((sR[0] == INT_MAX) ? 0 : sR[0]);

#define PDECL(j) float a##j = 0.0f;
#define PACC(j)  a##j = fmaf(f, w1[(j) * kIN + i], a##j);
#define PATOM(j) unsafeAtomicAdd(dst + (j), a##j);

    if (tid < 192) {
        // band columns -> Pa, uses W1[:, CH:] (acquired half)
        const float* w1 = W1 + kCH;
        for (int w = left + tid; w < right; w += 192) {
            E18(PDECL)
            const float* col = acquired + ((size_t)(b * kCH + i0) * kW + w) * 2;
#pragma unroll 4
            for (int ii = 0; ii < ROWS; ++ii) {
                const float2 v = *reinterpret_cast<const float2*>(col);
                col += 2 * kW;
                float f = sqrtf(v.x * v.x + v.y * v.y);
                int i = i0 + ii;
                E18(PACC)
            }
            float* dst = Pa + ((size_t)(b * kW) + w) * kNC;
            E18(PATOM)
        }
    } else {
        // acquiring columns -> Pq, uses W1[:, :CH] (acquiring half)
        int local = tid & 63;
        const float* w1 = W1;
        int bw = b * kW;
        for (int base = 0;; base += 64) {
            int target = base + local;
            int cnt = 0, mycol = -1;
            for (int w = 0; w < kW; ++w)
                if (qm[bw + w] > 0.0f) { if (cnt == target) mycol = w; cnt++; }
            if (mycol >= 0) {
                E18(PDECL)
                const float* col = acquiring + ((size_t)(b * kCH + i0) * kW + mycol) * 2;
#pragma unroll 4
                for (int ii = 0; ii < ROWS; ++ii) {
                    const float2 v = *reinterpret_cast<const float2*>(col);
                    col += 2 * kW;
                    float f = sqrtf(v.x * v.x + v.y * v.y);
                    int i = i0 + ii;
                    E18(PACC)
                }
                float* dst = Pq + ((size_t)bw + mycol) * kNC;
                E18(PATOM)
            }
            if (base + 64 >= cnt) break;
        }
    }
}

// --------------------------------------------------------------------------
// K2: per acquiring column: heat = mean over wc in [left,right) of the MLP.
// Writes ONE float per active block (heat[b,w]). Fully scalarized MLP.
// --------------------------------------------------------------------------
__global__ __launch_bounds__(256)
void pair_kernel(const float* __restrict__ Pq, const float* __restrict__ Pa,
                 const float* __restrict__ am, const float* __restrict__ qmask,
                 const float* __restrict__ b1, const float* __restrict__ W2,
                 const float* __restrict__ b2, const float* __restrict__ W3,
                 const float* __restrict__ b3, const float* __restrict__ W4,
                 const float* __restrict__ b4, float* __restrict__ heat) {
    int wi = blockIdx.x, b = blockIdx.y, tid = threadIdx.x;
    if (!(qmask[b * kW + wi] > 0.0f)) return;

    __shared__ int sL[256], sR[256];
    int candR = INT_MAX, candL = INT_MAX;
    for (int i = tid; i < kW - kMID; i += 256)
        if (am[b * kW + kMID + i] < 1.0f) candR = min(candR, i);
    for (int i = tid; i < kMID; i += 256)
        if (am[b * kW + (kMID - 1 - i)] < 1.0f) candL = min(candL, i);
    sL[tid] = candL; sR[tid] = candR;
    __syncthreads();
    for (int s = 128; s > 0; s >>= 1) {
        if (tid < s) {
            sL[tid] = min(sL[tid], sL[tid + s]);
            sR[tid] = min(sR[tid], sR[tid + s]);
        }
        __syncthreads();
    }
    int left  = ((sL[0] == INT_MAX) ? 0 : sL[0]) + 1;
    int right = kMID + ((sR[0] == INT_MAX) ? 0 : sR[0]);

    __shared__ float sW2[kNC * kNC], sW3[kNC * kNC], sW4[kNC];
    __shared__ float sb1[kNC], sb2[kNC], sb3[kNC], sPq[kNC];
    __shared__ float sb4, wred[4];
    for (int i = tid; i < kNC * kNC; i += 256) { sW2[i] = W2[i]; sW3[i] = W3[i]; }
    if (tid < kNC) {
        sW4[tid] = W4[tid]; sb1[tid] = b1[tid]; sb2[tid] = b2[tid]; sb3[tid] = b3[tid];
        sPq[tid] = Pq[((size_t)(b * kW + wi)) * kNC + tid];
    }
    if (tid == 0) sb4 = b4[0];
    __syncthreads();

#define DOTX(Wm, r) (Wm[(r)*kNC+ 0]*x0 + Wm[(r)*kNC+ 1]*x1 + Wm[(r)*kNC+ 2]*x2 + \
                     Wm[(r)*kNC+ 3]*x3 + Wm[(r)*kNC+ 4]*x4 + Wm[(r)*kNC+ 5]*x5 + \
                     Wm[(r)*kNC+ 6]*x6 + Wm[(r)*kNC+ 7]*x7 + Wm[(r)*kNC+ 8]*x8 + \
                     Wm[(r)*kNC+ 9]*x9 + Wm[(r)*kNC+10]*x10 + Wm[(r)*kNC+11]*x11 + \
                     Wm[(r)*kNC+12]*x12 + Wm[(r)*kNC+13]*x13 + Wm[(r)*kNC+14]*x14 + \
                     Wm[(r)*kNC+15]*x15 + Wm[(r)*kNC+16]*x16 + Wm[(r)*kNC+17]*x17)
#define DOTY(Wm, r) (Wm[(r)*kNC+ 0]*y0 + Wm[(r)*kNC+ 1]*y1 + Wm[(r)*kNC+ 2]*y2 + \
                     Wm[(r)*kNC+ 3]*y3 + Wm[(r)*kNC+ 4]*y4 + Wm[(r)*kNC+ 5]*y5 + \
                     Wm[(r)*kNC+ 6]*y6 + Wm[(r)*kNC+ 7]*y7 + Wm[(r)*kNC+ 8]*y8 + \
                     Wm[(r)*kNC+ 9]*y9 + Wm[(r)*kNC+10]*y10 + Wm[(r)*kNC+11]*y11 + \
                     Wm[(r)*kNC+12]*y12 + Wm[(r)*kNC+13]*y13 + Wm[(r)*kNC+14]*y14 + \
                     Wm[(r)*kNC+15]*y15 + Wm[(r)*kNC+16]*y16 + Wm[(r)*kNC+17]*y17)

    float ssum = 0.0f;
    for (int wc = left + tid; wc < right; wc += 256) {
        const float* pa = Pa + (size_t)(b * kW + wc) * kNC;
#define DX(i) float x##i = fmaxf(sPq[i] + pa[i] + sb1[i], 0.0f);
        E18(DX)
#define DY(i) float y##i = fmaxf(sb2[i] + DOTX(sW2, i), 0.0f);
        E18(DY)
#define DZ(i) float z##i = fmaxf(sb3[i] + DOTY(sW3, i), 0.0f);
        E18(DZ)
        float t = sb4 +
            (sW4[0]*z0 + sW4[1]*z1 + sW4[2]*z2 + sW4[3]*z3 + sW4[4]*z4 + sW4[5]*z5 +
             sW4[6]*z6 + sW4[7]*z7 + sW4[8]*z8 + sW4[9]*z9 + sW4[10]*z10 + sW4[11]*z11 +
             sW4[12]*z12 + sW4[13]*z13 + sW4[14]*z14 + sW4[15]*z15 + sW4[16]*z16 + sW4[17]*z17);
        ssum += 1.0f / (1.0f + expf(-t));
    }

    ssum += __shfl_down(ssum, 32, 64); ssum += __shfl_down(ssum, 16, 64);
    ssum += __shfl_down(ssum,  8, 64); ssum += __shfl_down(ssum,  4, 64);
    ssum += __shfl_down(ssum,  2, 64); ssum += __shfl_down(ssum,  1, 64);
    int wave = tid >> 6, lane = tid & 63;
    if (lane == 0) wred[wave] = ssum;
    __syncthreads();
    if (tid == 0)
        heat[b * kW + wi] = (wred[0] + wred[1] + wred[2] + wred[3]) / (float)(right - left);
}

// --------------------------------------------------------------------------
// K3: coalesced broadcast: out[b,h,w] = qmask ? heat[b,w] : 0
// --------------------------------------------------------------------------
__global__ __launch_bounds__(256)
void out_kernel(const float* __restrict__ heat, const float* __restrict__ qm,
                float* __restrict__ out) {
    int idx = blockIdx.x * 256 + threadIdx.x;
    if (idx >= kB * kH * kW) return;
    int w = idx % kW;
    int b = idx / (kH * kW);
    out[idx] = (qm[b * kW + w] > 0.0f) ? heat[b * kW + w] : 0.0f;
}

extern "C" void kernel_launch(void* const* d_in, const int* in_sizes, int n_in,
                              void* d_out, int out_size, void* d_ws, size_t ws_size,
                              hipStream_t stream) {
    const float* acquired       = (const float*)d_in[0];
    const float* acquiring      = (const float*)d_in[1];
    const float* acquired_mask  = (const float*)d_in[2];
    const float* acquiring_mask = (const float*)d_in[3];
    const float* W1 = (const float*)d_in[4];
    const float* b1 = (const float*)d_in[5];
    const float* W2 = (const float*)d_in[6];
    const float* b2 = (const float*)d_in[7];
    const float* W3 = (const float*)d_in[8];
    const float* b3 = (const float*)d_in[9];
    const float* W4 = (const float*)d_in[10];
    const float* b4 = (const float*)d_in[11];
    float* out = (float*)d_out;

    float* Pq   = (float*)d_ws;                    // B*W*18
    float* Pa   = Pq + (size_t)kB * kW * kNC;      // B*W*18
    float* heat = Pa + (size_t)kB * kW * kNC;      // B*W

    int nP = 2 * kB * kW * kNC;
    zero_kernel<<<(nP + 255) / 256, 256, 0, stream>>>(Pq);
    proj_kernel<<<dim3(NCHUNK, kB), 256, 0, stream>>>(acquired, acquiring, acquired_mask,
                                                      acquiring_mask, W1, Pq, Pa);
    pair_kernel<<<dim3(kW, kB), 256, 0, stream>>>(Pq, Pa, acquired_mask, acquiring_mask,
                                                  b1, W2, b2, W3, b3, W4, b4, heat);
    int n = kB * kH * kW;
    out_kernel<<<(n + 255) / 256, 256, 0, stream>>>(heat, acquiring_mask, out);
}

// Round 4
// 242.289 us; speedup vs baseline: 1.2111x; 1.2111x over previous
//
#include <hip/hip_runtime.h>
#include <math.h>
#include <limits.h>

#define kB 4
#define kC 8
#define kH 384
#define kW 384
#define kCH (kC * kH)   // 3072
#define kIN (2 * kCH)   // 6144
#define kNC 18
#define kMID (kW / 2)

#define NCH 4                 // row chunks
#define RPC (kCH / NCH)       // 768 rows per chunk
#define RSTAGE 192            // rows staged to LDS at a time
#define NSTAGE (RPC / RSTAGE) // 4
#define NGRP 48               // column groups of 8

#define E18(M) M(0) M(1) M(2) M(3) M(4) M(5) M(6) M(7) M(8) M(9) M(10) M(11) M(12) M(13) M(14) M(15) M(16) M(17)

// --------------------------------------------------------------------------
// K1: grid (48 col-groups, NCH row-chunks, B). 256 threads = 8 cols x 32 rows.
// Coalesced k-space reads (8 cols * 8B = full 64B line per row), W1 staged in
// LDS, per-block partial [8 cols][18] written to P_part (no atomics).
// --------------------------------------------------------------------------
__global__ __launch_bounds__(256)
void proj_kernel(const float* __restrict__ acquired,
                 const float* __restrict__ acquiring,
                 const float* __restrict__ am,
                 const float* __restrict__ qm,
                 const float* __restrict__ W1,
                 float* __restrict__ Pq_part, float* __restrict__ Pa_part) {
    int g = blockIdx.x, chunk = blockIdx.y, b = blockIdx.z;
    int tid = threadIdx.x;
    int w0 = g * 8;
    int r0 = chunk * RPC;

    // faithful left/right from acquired_mask (argmax(<1), 0 if none)
    __shared__ int sL[256], sR[256];
    __shared__ float sQm[8];
    int candR = INT_MAX, candL = INT_MAX;
    for (int i = tid; i < kW - kMID; i += 256)
        if (am[b * kW + kMID + i] < 1.0f) candR = min(candR, i);
    for (int i = tid; i < kMID; i += 256)
        if (am[b * kW + (kMID - 1 - i)] < 1.0f) candL = min(candL, i);
    sL[tid] = candL; sR[tid] = candR;
    if (tid < 8) sQm[tid] = qm[b * kW + w0 + tid];
    __syncthreads();
    for (int s = 128; s > 0; s >>= 1) {
        if (tid < s) {
            sL[tid] = min(sL[tid], sL[tid + s]);
            sR[tid] = min(sR[tid], sR[tid + s]);
        }
        __syncthreads();
    }
    int left  = ((sL[0] == INT_MAX) ? 0 : sL[0]) + 1;
    int right = kMID + ((sR[0] == INT_MAX) ? 0 : sR[0]);

    bool band = (left < w0 + 8) && (right > w0);
    bool acq_any = (sQm[0] > 0.f) || (sQm[1] > 0.f) || (sQm[2] > 0.f) || (sQm[3] > 0.f) ||
                   (sQm[4] > 0.f) || (sQm[5] > 0.f) || (sQm[6] > 0.f) || (sQm[7] > 0.f);
    if (!band && !acq_any) return;

    int c8 = tid & 7, r32 = tid >> 3;
    int w = w0 + c8;
    int lane = tid & 63, wave = tid >> 6;

    __shared__ float sW[RSTAGE][20];     // pad 20 keeps 16B row alignment
    __shared__ float sRed[4][8][kNC];

    for (int pass = 0; pass < 2; ++pass) {
        bool need = (pass == 0) ? band : acq_any;
        if (!need) continue;
        const float* ks = (pass == 0) ? acquired : acquiring;
        const float* w1 = (pass == 0) ? (W1 + kCH) : W1;   // acquired uses W1[:,CH:], acquiring W1[:,:CH]

#define PDECL(j) float a##j = 0.0f;
        E18(PDECL)

        for (int st = 0; st < NSTAGE; ++st) {
            int rs = r0 + st * RSTAGE;
            __syncthreads();
            for (int t = tid; t < kNC * RSTAGE; t += 256) {
                int j = t / RSTAGE, i = t - j * RSTAGE;
                sW[i][j] = w1[j * kIN + rs + i];
            }
            __syncthreads();
#pragma unroll
            for (int it = 0; it < RSTAGE / 32; ++it) {
                int rl = r32 + 32 * it;
                const float2 v = *reinterpret_cast<const float2*>(
                    ks + ((size_t)(b * kCH + rs + rl) * kW + w) * 2);
                float f = sqrtf(v.x * v.x + v.y * v.y);
                const float4 q0 = *reinterpret_cast<const float4*>(&sW[rl][0]);
                const float4 q1 = *reinterpret_cast<const float4*>(&sW[rl][4]);
                const float4 q2 = *reinterpret_cast<const float4*>(&sW[rl][8]);
                const float4 q3 = *reinterpret_cast<const float4*>(&sW[rl][12]);
                const float2 q4 = *reinterpret_cast<const float2*>(&sW[rl][16]);
                a0  = fmaf(f, q0.x, a0);  a1  = fmaf(f, q0.y, a1);
                a2  = fmaf(f, q0.z, a2);  a3  = fmaf(f, q0.w, a3);
                a4  = fmaf(f, q1.x, a4);  a5  = fmaf(f, q1.y, a5);
                a6  = fmaf(f, q1.z, a6);  a7  = fmaf(f, q1.w, a7);
                a8  = fmaf(f, q2.x, a8);  a9  = fmaf(f, q2.y, a9);
                a10 = fmaf(f, q2.z, a10); a11 = fmaf(f, q2.w, a11);
                a12 = fmaf(f, q3.x, a12); a13 = fmaf(f, q3.y, a13);
                a14 = fmaf(f, q3.z, a14); a15 = fmaf(f, q3.w, a15);
                a16 = fmaf(f, q4.x, a16); a17 = fmaf(f, q4.y, a17);
            }
        }
        // reduce 8 lanes with stride 8 (same column) within the wave
#define WRED(j) { a##j += __shfl_down(a##j, 32, 64); a##j += __shfl_down(a##j, 16, 64); \
                  a##j += __shfl_down(a##j, 8, 64); }
        E18(WRED)
        if (lane < 8) {
#define SSTORE(j) sRed[wave][lane][j] = a##j;
            E18(SSTORE)
        }
        __syncthreads();
        if (tid < 8 * kNC) {
            int c = tid / kNC, j = tid - c * kNC;
            float s = sRed[0][c][j] + sRed[1][c][j] + sRed[2][c][j] + sRed[3][c][j];
            float* Pp = (pass == 0) ? Pa_part : Pq_part;
            Pp[(((size_t)chunk * kB + b) * kW + (w0 + c)) * kNC + j] = s;
        }
    }
}

// --------------------------------------------------------------------------
// K2: per acquiring column wi: reduce chunk-partials for [left,right) into
// LDS, then heat[b,wi] = mean over wc of the scalarized MLP. One float out.
// --------------------------------------------------------------------------
__global__ __launch_bounds__(256)
void pair_kernel(const float* __restrict__ Pq_part, const float* __restrict__ Pa_part,
                 const float* __restrict__ am, const float* __restrict__ qmask,
                 const float* __restrict__ b1, const float* __restrict__ W2,
                 const float* __restrict__ b2, const float* __restrict__ W3,
                 const float* __restrict__ b3, const float* __restrict__ W4,
                 const float* __restrict__ b4, float* __restrict__ heat) {
    int wi = blockIdx.x, b = blockIdx.y, tid = threadIdx.x;
    if (!(qmask[b * kW + wi] > 0.0f)) return;

    __shared__ int sL[256], sR[256];
    int candR = INT_MAX, candL = INT_MAX;
    for (int i = tid; i < kW - kMID; i += 256)
        if (am[b * kW + kMID + i] < 1.0f) candR = min(candR, i);
    for (int i = tid; i < kMID; i += 256)
        if (am[b * kW + (kMID - 1 - i)] < 1.0f) candL = min(candL, i);
    sL[tid] = candL; sR[tid] = candR;
    __syncthreads();
    for (int s = 128; s > 0; s >>= 1) {
        if (tid < s) {
            sL[tid] = min(sL[tid], sL[tid + s]);
            sR[tid] = min(sR[tid], sR[tid + s]);
        }
        __syncthreads();
    }
    int left  = ((sL[0] == INT_MAX) ? 0 : sL[0]) + 1;
    int right = kMID + ((sR[0] == INT_MAX) ? 0 : sR[0]);
    int span = right - left;

    __shared__ float sPa[kW * kNC / 2 * 2];  // 384*18 floats worst case (span<384)
    __shared__ float sW2[kNC * kNC], sW3[kNC * kNC], sW4[kNC];
    __shared__ float sb1[kNC], sb2[kNC], sb3[kNC], sPq[kNC];
    __shared__ float sb4, wred[4];

    // reduce Pa partials over chunks into LDS (coalesced)
    for (int t = tid; t < span * kNC; t += 256) {
        int wc = left + t / kNC, j = t - (t / kNC) * kNC;
        float s = 0.0f;
#pragma unroll
        for (int c = 0; c < NCH; ++c)
            s += Pa_part[(((size_t)c * kB + b) * kW + wc) * kNC + j];
        sPa[t] = s;
    }
    for (int i = tid; i < kNC * kNC; i += 256) { sW2[i] = W2[i]; sW3[i] = W3[i]; }
    if (tid < kNC) {
        float s = 0.0f;
#pragma unroll
        for (int c = 0; c < NCH; ++c)
            s += Pq_part[(((size_t)c * kB + b) * kW + wi) * kNC + tid];
        sPq[tid] = s;
        sW4[tid] = W4[tid]; sb1[tid] = b1[tid]; sb2[tid] = b2[tid]; sb3[tid] = b3[tid];
    }
    if (tid == 0) sb4 = b4[0];
    __syncthreads();

#define DOTX(Wm, r) (Wm[(r)*kNC+ 0]*x0 + Wm[(r)*kNC+ 1]*x1 + Wm[(r)*kNC+ 2]*x2 + \
                     Wm[(r)*kNC+ 3]*x3 + Wm[(r)*kNC+ 4]*x4 + Wm[(r)*kNC+ 5]*x5 + \
                     Wm[(r)*kNC+ 6]*x6 + Wm[(r)*kNC+ 7]*x7 + Wm[(r)*kNC+ 8]*x8 + \
                     Wm[(r)*kNC+ 9]*x9 + Wm[(r)*kNC+10]*x10 + Wm[(r)*kNC+11]*x11 + \
                     Wm[(r)*kNC+12]*x12 + Wm[(r)*kNC+13]*x13 + Wm[(r)*kNC+14]*x14 + \
                     Wm[(r)*kNC+15]*x15 + Wm[(r)*kNC+16]*x16 + Wm[(r)*kNC+17]*x17)
#define DOTY(Wm, r) (Wm[(r)*kNC+ 0]*y0 + Wm[(r)*kNC+ 1]*y1 + Wm[(r)*kNC+ 2]*y2 + \
                     Wm[(r)*kNC+ 3]*y3 + Wm[(r)*kNC+ 4]*y4 + Wm[(r)*kNC+ 5]*y5 + \
                     Wm[(r)*kNC+ 6]*y6 + Wm[(r)*kNC+ 7]*y7 + Wm[(r)*kNC+ 8]*y8 + \
                     Wm[(r)*kNC+ 9]*y9 + Wm[(r)*kNC+10]*y10 + Wm[(r)*kNC+11]*y11 + \
                     Wm[(r)*kNC+12]*y12 + Wm[(r)*kNC+13]*y13 + Wm[(r)*kNC+14]*y14 + \
                     Wm[(r)*kNC+15]*y15 + Wm[(r)*kNC+16]*y16 + Wm[(r)*kNC+17]*y17)

    float ssum = 0.0f;
    for (int wc = left + tid; wc < right; wc += 256) {
        const float* pa = &sPa[(wc - left) * kNC];
#define DX(i) float x##i = fmaxf(sPq[i] + pa[i] + sb1[i], 0.0f);
        E18(DX)
#define DY(i) float y##i = fmaxf(sb2[i] + DOTX(sW2, i), 0.0f);
        E18(DY)
#define DZ(i) float z##i = fmaxf(sb3[i] + DOTY(sW3, i), 0.0f);
        E18(DZ)
        float t = sb4 +
            (sW4[0]*z0 + sW4[1]*z1 + sW4[2]*z2 + sW4[3]*z3 + sW4[4]*z4 + sW4[5]*z5 +
             sW4[6]*z6 + sW4[7]*z7 + sW4[8]*z8 + sW4[9]*z9 + sW4[10]*z10 + sW4[11]*z11 +
             sW4[12]*z12 + sW4[13]*z13 + sW4[14]*z14 + sW4[15]*z15 + sW4[16]*z16 + sW4[17]*z17);
        ssum += 1.0f / (1.0f + expf(-t));
    }

    ssum += __shfl_down(ssum, 32, 64); ssum += __shfl_down(ssum, 16, 64);
    ssum += __shfl_down(ssum,  8, 64); ssum += __shfl_down(ssum,  4, 64);
    ssum += __shfl_down(ssum,  2, 64); ssum += __shfl_down(ssum,  1, 64);
    int wave = tid >> 6, lane = tid & 63;
    if (lane == 0) wred[wave] = ssum;
    __syncthreads();
    if (tid == 0)
        heat[b * kW + wi] = (wred[0] + wred[1] + wred[2] + wred[3]) / (float)span;
}

// --------------------------------------------------------------------------
// K3: coalesced broadcast: out[b,h,w] = qmask ? heat[b,w] : 0
// --------------------------------------------------------------------------
__global__ __launch_bounds__(256)
void out_kernel(const float* __restrict__ heat, const float* __restrict__ qm,
                float* __restrict__ out) {
    int idx = blockIdx.x * 256 + threadIdx.x;
    if (idx >= kB * kH * kW) return;
    int w = idx % kW;
    int b = idx / (kH * kW);
    out[idx] = (qm[b * kW + w] > 0.0f) ? heat[b * kW + w] : 0.0f;
}

extern "C" void kernel_launch(void* const* d_in, const int* in_sizes, int n_in,
                              void* d_out, int out_size, void* d_ws, size_t ws_size,
                              hipStream_t stream) {
    const float* acquired       = (const float*)d_in[0];
    const float* acquiring      = (const float*)d_in[1];
    const float* acquired_mask  = (const float*)d_in[2];
    const float* acquiring_mask = (const float*)d_in[3];
    const float* W1 = (const float*)d_in[4];
    const float* b1 = (const float*)d_in[5];
    const float* W2 = (const float*)d_in[6];
    const float* b2 = (const float*)d_in[7];
    const float* W3 = (const float*)d_in[8];
    const float* b3 = (const float*)d_in[9];
    const float* W4 = (const float*)d_in[10];
    const float* b4 = (const float*)d_in[11];
    float* out = (float*)d_out;

    size_t partN = (size_t)NCH * kB * kW * kNC;   // 110592 floats
    float* Pa_part = (float*)d_ws;
    float* Pq_part = Pa_part + partN;
    float* heat    = Pq_part + partN;             // + kB*kW

    proj_kernel<<<dim3(NGRP, NCH, kB), 256, 0, stream>>>(
        acquired, acquiring, acquired_mask, acquiring_mask, W1, Pq_part, Pa_part);
    pair_kernel<<<dim3(kW, kB), 256, 0, stream>>>(
        Pq_part, Pa_part, acquired_mask, acquiring_mask,
        b1, W2, b2, W3, b3, W4, b4, heat);
    int n = kB * kH * kW;
    out_kernel<<<(n + 255) / 256, 256, 0, stream>>>(heat, acquiring_mask, out);
}

// Round 5
// 165.848 us; speedup vs baseline: 1.7693x; 1.4609x over previous
//
#include <hip/hip_runtime.h>
#include <math.h>
#include <limits.h>

#define kB 4
#define kC 8
#define kH 384
#define kW 384
#define kCH (kC * kH)   // 3072
#define kIN (2 * kCH)   // 6144
#define kNC 18
#define kMID (kW / 2)

#define NCH 4                 // row chunks
#define RPC (kCH / NCH)       // 768 rows per chunk
#define RSTAGE 192            // rows staged to LDS at a time
#define NSTAGE (RPC / RSTAGE) // 4
#define NGRP 48               // column groups of 8

#define E18(M) M(0) M(1) M(2) M(3) M(4) M(5) M(6) M(7) M(8) M(9) M(10) M(11) M(12) M(13) M(14) M(15) M(16) M(17)

// --------------------------------------------------------------------------
// K1: grid (48 col-groups, NCH row-chunks, B). 256 threads = 8 cols x 32 rows.
// Coalesced k-space reads (8 cols * 8B = full 64B line per row), W1 staged in
// LDS, per-block partial [8 cols][18] written to P_part (no atomics).
// --------------------------------------------------------------------------
__global__ __launch_bounds__(256)
void proj_kernel(const float* __restrict__ acquired,
                 const float* __restrict__ acquiring,
                 const float* __restrict__ am,
                 const float* __restrict__ qm,
                 const float* __restrict__ W1,
                 float* __restrict__ Pq_part, float* __restrict__ Pa_part) {
    int g = blockIdx.x, chunk = blockIdx.y, b = blockIdx.z;
    int tid = threadIdx.x;
    int w0 = g * 8;
    int r0 = chunk * RPC;

    // faithful left/right from acquired_mask (argmax(<1), 0 if none)
    __shared__ int sL[256], sR[256];
    __shared__ float sQm[8];
    int candR = INT_MAX, candL = INT_MAX;
    for (int i = tid; i < kW - kMID; i += 256)
        if (am[b * kW + kMID + i] < 1.0f) candR = min(candR, i);
    for (int i = tid; i < kMID; i += 256)
        if (am[b * kW + (kMID - 1 - i)] < 1.0f) candL = min(candL, i);
    sL[tid] = candL; sR[tid] = candR;
    if (tid < 8) sQm[tid] = qm[b * kW + w0 + tid];
    __syncthreads();
    for (int s = 128; s > 0; s >>= 1) {
        if (tid < s) {
            sL[tid] = min(sL[tid], sL[tid + s]);
            sR[tid] = min(sR[tid], sR[tid + s]);
        }
        __syncthreads();
    }
    int left  = ((sL[0] == INT_MAX) ? 0 : sL[0]) + 1;
    int right = kMID + ((sR[0] == INT_MAX) ? 0 : sR[0]);

    bool band = (left < w0 + 8) && (right > w0);
    bool acq_any = (sQm[0] > 0.f) || (sQm[1] > 0.f) || (sQm[2] > 0.f) || (sQm[3] > 0.f) ||
                   (sQm[4] > 0.f) || (sQm[5] > 0.f) || (sQm[6] > 0.f) || (sQm[7] > 0.f);
    if (!band && !acq_any) return;

    int c8 = tid & 7, r32 = tid >> 3;
    int w = w0 + c8;
    int lane = tid & 63, wave = tid >> 6;

    __shared__ float sW[RSTAGE][20];     // pad 20 keeps 16B row alignment
    __shared__ float sRed[4][8][kNC];

    for (int pass = 0; pass < 2; ++pass) {
        bool need = (pass == 0) ? band : acq_any;
        if (!need) continue;
        const float* ks = (pass == 0) ? acquired : acquiring;
        const float* w1 = (pass == 0) ? (W1 + kCH) : W1;   // acquired uses W1[:,CH:], acquiring W1[:,:CH]

#define PDECL(j) float a##j = 0.0f;
        E18(PDECL)

        for (int st = 0; st < NSTAGE; ++st) {
            int rs = r0 + st * RSTAGE;
            __syncthreads();
            for (int t = tid; t < kNC * RSTAGE; t += 256) {
                int j = t / RSTAGE, i = t - j * RSTAGE;
                sW[i][j] = w1[j * kIN + rs + i];
            }
            __syncthreads();
#pragma unroll
            for (int it = 0; it < RSTAGE / 32; ++it) {
                int rl = r32 + 32 * it;
                const float2 v = *reinterpret_cast<const float2*>(
                    ks + ((size_t)(b * kCH + rs + rl) * kW + w) * 2);
                float f = sqrtf(v.x * v.x + v.y * v.y);
                const float4 q0 = *reinterpret_cast<const float4*>(&sW[rl][0]);
                const float4 q1 = *reinterpret_cast<const float4*>(&sW[rl][4]);
                const float4 q2 = *reinterpret_cast<const float4*>(&sW[rl][8]);
                const float4 q3 = *reinterpret_cast<const float4*>(&sW[rl][12]);
                const float2 q4 = *reinterpret_cast<const float2*>(&sW[rl][16]);
                a0  = fmaf(f, q0.x, a0);  a1  = fmaf(f, q0.y, a1);
                a2  = fmaf(f, q0.z, a2);  a3  = fmaf(f, q0.w, a3);
                a4  = fmaf(f, q1.x, a4);  a5  = fmaf(f, q1.y, a5);
                a6  = fmaf(f, q1.z, a6);  a7  = fmaf(f, q1.w, a7);
                a8  = fmaf(f, q2.x, a8);  a9  = fmaf(f, q2.y, a9);
                a10 = fmaf(f, q2.z, a10); a11 = fmaf(f, q2.w, a11);
                a12 = fmaf(f, q3.x, a12); a13 = fmaf(f, q3.y, a13);
                a14 = fmaf(f, q3.z, a14); a15 = fmaf(f, q3.w, a15);
                a16 = fmaf(f, q4.x, a16); a17 = fmaf(f, q4.y, a17);
            }
        }
        // reduce 8 lanes with stride 8 (same column) within the wave
#define WRED(j) { a##j += __shfl_down(a##j, 32, 64); a##j += __shfl_down(a##j, 16, 64); \
                  a##j += __shfl_down(a##j, 8, 64); }
        E18(WRED)
        if (lane < 8) {
#define SSTORE(j) sRed[wave][lane][j] = a##j;
            E18(SSTORE)
        }
        __syncthreads();
        if (tid < 8 * kNC) {
            int c = tid / kNC, j = tid - c * kNC;
            float s = sRed[0][c][j] + sRed[1][c][j] + sRed[2][c][j] + sRed[3][c][j];
            float* Pp = (pass == 0) ? Pa_part : Pq_part;
            Pp[(((size_t)chunk * kB + b) * kW + (w0 + c)) * kNC + j] = s;
        }
    }
}

// --------------------------------------------------------------------------
// K2: per acquiring column wi: heat[b,wi] = mean over wc in [left,right) of
// the 3-layer MLP + sigmoid. Registers for x/y/z, asm fences between layers
// to stop load hoisting (R4 spilled: VGPR 256, 16.5MB scratch writes).
// Weights in LDS as float2 (uniform ds_read_b64 broadcasts).
// --------------------------------------------------------------------------
__global__ __launch_bounds__(256)
void pair_kernel(const float* __restrict__ Pq_part, const float* __restrict__ Pa_part,
                 const float* __restrict__ am, const float* __restrict__ qmask,
                 const float* __restrict__ b1, const float* __restrict__ W2,
                 const float* __restrict__ b2, const float* __restrict__ W3,
                 const float* __restrict__ b3, const float* __restrict__ W4,
                 const float* __restrict__ b4, float* __restrict__ heat) {
    int wi = blockIdx.x, b = blockIdx.y, tid = threadIdx.x;
    if (!(qmask[b * kW + wi] > 0.0f)) return;

    __shared__ int sL[256], sR[256];
    int candR = INT_MAX, candL = INT_MAX;
    for (int i = tid; i < kW - kMID; i += 256)
        if (am[b * kW + kMID + i] < 1.0f) candR = min(candR, i);
    for (int i = tid; i < kMID; i += 256)
        if (am[b * kW + (kMID - 1 - i)] < 1.0f) candL = min(candL, i);
    sL[tid] = candL; sR[tid] = candR;
    __syncthreads();
    for (int s = 128; s > 0; s >>= 1) {
        if (tid < s) {
            sL[tid] = min(sL[tid], sL[tid + s]);
            sR[tid] = min(sR[tid], sR[tid + s]);
        }
        __syncthreads();
    }
    int left  = ((sL[0] == INT_MAX) ? 0 : sL[0]) + 1;
    int right = kMID + ((sR[0] == INT_MAX) ? 0 : sR[0]);
    int span = right - left;

    __shared__ float2 sW2[kNC * kNC / 2], sW3[kNC * kNC / 2];   // row-major pairs
    __shared__ float sW4[kNC], sb1[kNC], sb2[kNC], sb3[kNC], sPq[kNC];
    __shared__ float sb4s, wred[4];
    if (tid < kNC * kNC / 2) {
        sW2[tid] = reinterpret_cast<const float2*>(W2)[tid];
        sW3[tid] = reinterpret_cast<const float2*>(W3)[tid];
    }
    if (tid >= 192 && tid < 192 + kNC) {
        int j = tid - 192;
        float s = 0.0f;
#pragma unroll
        for (int c = 0; c < NCH; ++c)
            s += Pq_part[(((size_t)c * kB + b) * kW + wi) * kNC + j];
        sPq[j] = s;
        sW4[j] = W4[j]; sb1[j] = b1[j]; sb2[j] = b2[j]; sb3[j] = b3[j];
    }
    if (tid == 255) sb4s = b4[0];
    __syncthreads();

#define DOT2(S, k, v) (S[(k)*9+0].x*v##0  + S[(k)*9+0].y*v##1  + \
                       S[(k)*9+1].x*v##2  + S[(k)*9+1].y*v##3  + \
                       S[(k)*9+2].x*v##4  + S[(k)*9+2].y*v##5  + \
                       S[(k)*9+3].x*v##6  + S[(k)*9+3].y*v##7  + \
                       S[(k)*9+4].x*v##8  + S[(k)*9+4].y*v##9  + \
                       S[(k)*9+5].x*v##10 + S[(k)*9+5].y*v##11 + \
                       S[(k)*9+6].x*v##12 + S[(k)*9+6].y*v##13 + \
                       S[(k)*9+7].x*v##14 + S[(k)*9+7].y*v##15 + \
                       S[(k)*9+8].x*v##16 + S[(k)*9+8].y*v##17)

    float ssum = 0.0f;
    for (int wc = left + tid; wc < right; wc += 256) {
        const float* pa0 = Pa_part + (((size_t)0 * kB + b) * kW + wc) * kNC;
        const float* pa1 = Pa_part + (((size_t)1 * kB + b) * kW + wc) * kNC;
        const float* pa2 = Pa_part + (((size_t)2 * kB + b) * kW + wc) * kNC;
        const float* pa3 = Pa_part + (((size_t)3 * kB + b) * kW + wc) * kNC;
#define L1(j) float x##j = fmaxf(sPq[j] + sb1[j] + ((pa0[j] + pa1[j]) + (pa2[j] + pa3[j])), 0.0f);
        E18(L1)
        asm volatile("" ::: "memory");
#define L2(k) float y##k = fmaxf(sb2[k] + DOT2(sW2, k, x), 0.0f);
        E18(L2)
        asm volatile("" ::: "memory");
#define L3(k) float z##k = fmaxf(sb3[k] + DOT2(sW3, k, y), 0.0f);
        E18(L3)
        asm volatile("" ::: "memory");
        float t = sb4s +
            (sW4[0]*z0 + sW4[1]*z1 + sW4[2]*z2 + sW4[3]*z3 + sW4[4]*z4 + sW4[5]*z5 +
             sW4[6]*z6 + sW4[7]*z7 + sW4[8]*z8 + sW4[9]*z9 + sW4[10]*z10 + sW4[11]*z11 +
             sW4[12]*z12 + sW4[13]*z13 + sW4[14]*z14 + sW4[15]*z15 + sW4[16]*z16 + sW4[17]*z17);
        ssum += 1.0f / (1.0f + expf(-t));
    }

    ssum += __shfl_down(ssum, 32, 64); ssum += __shfl_down(ssum, 16, 64);
    ssum += __shfl_down(ssum,  8, 64); ssum += __shfl_down(ssum,  4, 64);
    ssum += __shfl_down(ssum,  2, 64); ssum += __shfl_down(ssum,  1, 64);
    int wave = tid >> 6, lane = tid & 63;
    if (lane == 0) wred[wave] = ssum;
    __syncthreads();
    if (tid == 0)
        heat[b * kW + wi] = (wred[0] + wred[1] + wred[2] + wred[3]) / (float)span;
}

// --------------------------------------------------------------------------
// K3: coalesced broadcast: out[b,h,w] = qmask ? heat[b,w] : 0
// --------------------------------------------------------------------------
__global__ __launch_bounds__(256)
void out_kernel(const float* __restrict__ heat, const float* __restrict__ qm,
                float* __restrict__ out) {
    int idx = blockIdx.x * 256 + threadIdx.x;
    if (idx >= kB * kH * kW) return;
    int w = idx % kW;
    int b = idx / (kH * kW);
    out[idx] = (qm[b * kW + w] > 0.0f) ? heat[b * kW + w] : 0.0f;
}

extern "C" void kernel_launch(void* const* d_in, const int* in_sizes, int n_in,
                              void* d_out, int out_size, void* d_ws, size_t ws_size,
                              hipStream_t stream) {
    const float* acquired       = (const float*)d_in[0];
    const float* acquiring      = (const float*)d_in[1];
    const float* acquired_mask  = (const float*)d_in[2];
    const float* acquiring_mask = (const float*)d_in[3];
    const float* W1 = (const float*)d_in[4];
    const float* b1 = (const float*)d_in[5];
    const float* W2 = (const float*)d_in[6];
    const float* b2 = (const float*)d_in[7];
    const float* W3 = (const float*)d_in[8];
    const float* b3 = (const float*)d_in[9];
    const float* W4 = (const float*)d_in[10];
    const float* b4 = (const float*)d_in[11];
    float* out = (float*)d_out;

    size_t partN = (size_t)NCH * kB * kW * kNC;   // 110592 floats
    float* Pa_part = (float*)d_ws;
    float* Pq_part = Pa_part + partN;
    float* heat    = Pq_part + partN;             // + kB*kW

    proj_kernel<<<dim3(NGRP, NCH, kB), 256, 0, stream>>>(
        acquired, acquiring, acquired_mask, acquiring_mask, W1, Pq_part, Pa_part);
    pair_kernel<<<dim3(kW, kB), 256, 0, stream>>>(
        Pq_part, Pa_part, acquired_mask, acquiring_mask,
        b1, W2, b2, W3, b3, W4, b4, heat);
    int n = kB * kH * kW;
    out_kernel<<<(n + 255) / 256, 256, 0, stream>>>(heat, acquiring_mask, out);
}

// Round 6
// 148.668 us; speedup vs baseline: 1.9738x; 1.1156x over previous
//
#include <hip/hip_runtime.h>
#include <math.h>
#include <limits.h>

#define kB 4
#define kC 8
#define kH 384
#define kW 384
#define kCH (kC * kH)   // 3072
#define kIN (2 * kCH)   // 6144
#define kNC 18
#define kMID (kW / 2)

#define NCH 8                 // row chunks
#define RPC (kCH / NCH)       // 384 rows per chunk
#define NGRP 48               // column groups of 8
#define kN (kB * kW * kNC)    // 27648 floats per dense P array

#define E18(M) M(0) M(1) M(2) M(3) M(4) M(5) M(6) M(7) M(8) M(9) M(10) M(11) M(12) M(13) M(14) M(15) M(16) M(17)
#define E12(M) M(0) M(1) M(2) M(3) M(4) M(5) M(6) M(7) M(8) M(9) M(10) M(11)

// --------------------------------------------------------------------------
// K1: grid (48 col-groups, 8 row-chunks, B). 256 threads = 8 cols x 32 rows.
// Per pass: hoist all 12 k-space float2 loads into registers (one latency
// exposure, 12 loads in flight), stage the whole 384-row W1 chunk to LDS
// once (2 barriers/pass instead of 8), then LDS-vector FMA. Partials out.
// --------------------------------------------------------------------------
__global__ __launch_bounds__(256)
void proj_kernel(const float* __restrict__ acquired,
                 const float* __restrict__ acquiring,
                 const float* __restrict__ am,
                 const float* __restrict__ qm,
                 const float* __restrict__ W1,
                 float* __restrict__ Pq_part, float* __restrict__ Pa_part) {
    int g = blockIdx.x, chunk = blockIdx.y, b = blockIdx.z;
    int tid = threadIdx.x;
    int w0 = g * 8;
    int r0 = chunk * RPC;

    // faithful left/right from acquired_mask (argmax(<1), 0 if none)
    __shared__ int sL[256], sR[256];
    __shared__ float sQm[8];
    int candR = INT_MAX, candL = INT_MAX;
    for (int i = tid; i < kW - kMID; i += 256)
        if (am[b * kW + kMID + i] < 1.0f) candR = min(candR, i);
    for (int i = tid; i < kMID; i += 256)
        if (am[b * kW + (kMID - 1 - i)] < 1.0f) candL = min(candL, i);
    sL[tid] = candL; sR[tid] = candR;
    if (tid < 8) sQm[tid] = qm[b * kW + w0 + tid];
    __syncthreads();
    for (int s = 128; s > 0; s >>= 1) {
        if (tid < s) {
            sL[tid] = min(sL[tid], sL[tid + s]);
            sR[tid] = min(sR[tid], sR[tid + s]);
        }
        __syncthreads();
    }
    int left  = ((sL[0] == INT_MAX) ? 0 : sL[0]) + 1;
    int right = kMID + ((sR[0] == INT_MAX) ? 0 : sR[0]);

    bool band = (left < w0 + 8) && (right > w0);
    bool acq_any = (sQm[0] > 0.f) || (sQm[1] > 0.f) || (sQm[2] > 0.f) || (sQm[3] > 0.f) ||
                   (sQm[4] > 0.f) || (sQm[5] > 0.f) || (sQm[6] > 0.f) || (sQm[7] > 0.f);
    if (!band && !acq_any) return;

    int c8 = tid & 7, r32 = tid >> 3;
    int w = w0 + c8;
    int lane = tid & 63, wave = tid >> 6;

    __shared__ float sW[RPC][20];        // 30720 B; 80B rows keep 16B alignment
    __shared__ float sRed[4][8][kNC];

    for (int pass = 0; pass < 2; ++pass) {
        bool need = (pass == 0) ? band : acq_any;
        if (!need) continue;
        const float* ks = (pass == 0) ? acquired : acquiring;
        const float* w1 = (pass == 0) ? (W1 + kCH) : W1;  // acquired->W1[:,CH:], acquiring->W1[:,:CH]

        // ---- hoist all k-space loads (rows r32 + 32*it), coalesced 64B/row
        const float* colp = ks + ((size_t)(b * kCH + r0 + r32) * kW + w) * 2;
#define KLOAD(it) const float2 v##it = *reinterpret_cast<const float2*>(colp + (size_t)(it) * 32 * kW * 2);
        E12(KLOAD)
#define KMAG(it) const float f##it = sqrtf(v##it.x * v##it.x + v##it.y * v##it.y);
        E12(KMAG)

        // ---- stage W1 chunk (overlaps with k-loads above until barrier)
        __syncthreads();   // protect sW reuse across passes
        for (int t = tid; t < kNC * RPC; t += 256) {
            int j = t / RPC, i = t - j * RPC;
            sW[i][j] = w1[j * kIN + r0 + i];
        }
        __syncthreads();

#define PDECL(j) float a##j = 0.0f;
        E18(PDECL)

#define ROWF(it) { \
            const float* row = &sW[r32 + 32 * (it)][0]; \
            const float4 q0 = *reinterpret_cast<const float4*>(row); \
            const float4 q1 = *reinterpret_cast<const float4*>(row + 4); \
            const float4 q2 = *reinterpret_cast<const float4*>(row + 8); \
            const float4 q3 = *reinterpret_cast<const float4*>(row + 12); \
            const float2 q4 = *reinterpret_cast<const float2*>(row + 16); \
            const float f = f##it; \
            a0  = fmaf(f, q0.x, a0);  a1  = fmaf(f, q0.y, a1);  \
            a2  = fmaf(f, q0.z, a2);  a3  = fmaf(f, q0.w, a3);  \
            a4  = fmaf(f, q1.x, a4);  a5  = fmaf(f, q1.y, a5);  \
            a6  = fmaf(f, q1.z, a6);  a7  = fmaf(f, q1.w, a7);  \
            a8  = fmaf(f, q2.x, a8);  a9  = fmaf(f, q2.y, a9);  \
            a10 = fmaf(f, q2.z, a10); a11 = fmaf(f, q2.w, a11); \
            a12 = fmaf(f, q3.x, a12); a13 = fmaf(f, q3.y, a13); \
            a14 = fmaf(f, q3.z, a14); a15 = fmaf(f, q3.w, a15); \
            a16 = fmaf(f, q4.x, a16); a17 = fmaf(f, q4.y, a17); }
        E12(ROWF)

        // reduce lanes with stride 8 (same column) within the wave
#define WRED(j) { a##j += __shfl_down(a##j, 32, 64); a##j += __shfl_down(a##j, 16, 64); \
                  a##j += __shfl_down(a##j, 8, 64); }
        E18(WRED)
        if (lane < 8) {
#define SSTORE(j) sRed[wave][lane][j] = a##j;
            E18(SSTORE)
        }
        __syncthreads();
        if (tid < 8 * kNC) {
            int c = tid / kNC, j = tid - c * kNC;
            float s = sRed[0][c][j] + sRed[1][c][j] + sRed[2][c][j] + sRed[3][c][j];
            float* Pp = (pass == 0) ? Pa_part : Pq_part;
            Pp[((size_t)chunk * kB * kW + (size_t)b * kW + (w0 + c)) * kNC + j] = s;
        }
    }
}

// --------------------------------------------------------------------------
// K2: dense reduce of the 8 chunk-partials: P[n] = sum_c P_part[c*kN + n].
// Handles Pa (idx < kN) and Pq (idx >= kN). Fully coalesced.
// --------------------------------------------------------------------------
__global__ __launch_bounds__(256)
void reduce_kernel(const float* __restrict__ Pa_part, const float* __restrict__ Pq_part,
                   float* __restrict__ Pa, float* __restrict__ Pq) {
    int idx = blockIdx.x * 256 + threadIdx.x;
    if (idx >= 2 * kN) return;
    const float* src = (idx < kN) ? Pa_part : Pq_part;
    float* dst = (idx < kN) ? Pa : Pq;
    int n = (idx < kN) ? idx : idx - kN;
    float s = 0.0f;
#pragma unroll
    for (int c = 0; c < NCH; ++c) s += src[(size_t)c * kN + n];
    dst[n] = s;
}

// --------------------------------------------------------------------------
// K3: per acquiring column wi: heat = mean over wc in [left,right) of the
// 3-layer MLP + sigmoid. Scalar registers + asm fences (R5-proven, no spill).
// Weights in LDS as float2 broadcasts.
// --------------------------------------------------------------------------
__global__ __launch_bounds__(256)
void pair_kernel(const float* __restrict__ Pq, const float* __restrict__ Pa,
                 const float* __restrict__ am, const float* __restrict__ qmask,
                 const float* __restrict__ b1, const float* __restrict__ W2,
                 const float* __restrict__ b2, const float* __restrict__ W3,
                 const float* __restrict__ b3, const float* __restrict__ W4,
                 const float* __restrict__ b4, float* __restrict__ heat) {
    int wi = blockIdx.x, b = blockIdx.y, tid = threadIdx.x;
    if (!(qmask[b * kW + wi] > 0.0f)) return;

    __shared__ int sL[256], sR[256];
    int candR = INT_MAX, candL = INT_MAX;
    for (int i = tid; i < kW - kMID; i += 256)
        if (am[b * kW + kMID + i] < 1.0f) candR = min(candR, i);
    for (int i = tid; i < kMID; i += 256)
        if (am[b * kW + (kMID - 1 - i)] < 1.0f) candL = min(candL, i);
    sL[tid] = candL; sR[tid] = candR;
    __syncthreads();
    for (int s = 128; s > 0; s >>= 1) {
        if (tid < s) {
            sL[tid] = min(sL[tid], sL[tid + s]);
            sR[tid] = min(sR[tid], sR[tid + s]);
        }
        __syncthreads();
    }
    int left  = ((sL[0] == INT_MAX) ? 0 : sL[0]) + 1;
    int right = kMID + ((sR[0] == INT_MAX) ? 0 : sR[0]);
    int span = right - left;

    __shared__ float2 sW2[kNC * kNC / 2], sW3[kNC * kNC / 2];   // row-major pairs
    __shared__ float sW4[kNC], sb1[kNC], sb2[kNC], sb3[kNC], sPq[kNC];
    __shared__ float sb4s, wred[4];
    if (tid < kNC * kNC / 2) {
        sW2[tid] = reinterpret_cast<const float2*>(W2)[tid];
        sW3[tid] = reinterpret_cast<const float2*>(W3)[tid];
    }
    if (tid >= 192 && tid < 192 + kNC) {
        int j = tid - 192;
        sPq[j] = Pq[((size_t)(b * kW + wi)) * kNC + j];
        sW4[j] = W4[j]; sb1[j] = b1[j]; sb2[j] = b2[j]; sb3[j] = b3[j];
    }
    if (tid == 255) sb4s = b4[0];
    __syncthreads();

#define DOT2(S, k, v) (S[(k)*9+0].x*v##0  + S[(k)*9+0].y*v##1  + \
                       S[(k)*9+1].x*v##2  + S[(k)*9+1].y*v##3  + \
                       S[(k)*9+2].x*v##4  + S[(k)*9+2].y*v##5  + \
                       S[(k)*9+3].x*v##6  + S[(k)*9+3].y*v##7  + \
                       S[(k)*9+4].x*v##8  + S[(k)*9+4].y*v##9  + \
                       S[(k)*9+5].x*v##10 + S[(k)*9+5].y*v##11 + \
                       S[(k)*9+6].x*v##12 + S[(k)*9+6].y*v##13 + \
                       S[(k)*9+7].x*v##14 + S[(k)*9+7].y*v##15 + \
                       S[(k)*9+8].x*v##16 + S[(k)*9+8].y*v##17)

    float ssum = 0.0f;
    for (int wc = left + tid; wc < right; wc += 256) {
        const float* pa = Pa + (size_t)(b * kW + wc) * kNC;
#define L1(j) float x##j = fmaxf(sPq[j] + sb1[j] + pa[j], 0.0f);
        E18(L1)
        asm volatile("" ::: "memory");
#define L2(k) float y##k = fmaxf(sb2[k] + DOT2(sW2, k, x), 0.0f);
        E18(L2)
        asm volatile("" ::: "memory");
#define L3(k) float z##k = fmaxf(sb3[k] + DOT2(sW3, k, y), 0.0f);
        E18(L3)
        asm volatile("" ::: "memory");
        float t = sb4s +
            (sW4[0]*z0 + sW4[1]*z1 + sW4[2]*z2 + sW4[3]*z3 + sW4[4]*z4 + sW4[5]*z5 +
             sW4[6]*z6 + sW4[7]*z7 + sW4[8]*z8 + sW4[9]*z9 + sW4[10]*z10 + sW4[11]*z11 +
             sW4[12]*z12 + sW4[13]*z13 + sW4[14]*z14 + sW4[15]*z15 + sW4[16]*z16 + sW4[17]*z17);
        ssum += 1.0f / (1.0f + expf(-t));
    }

    ssum += __shfl_down(ssum, 32, 64); ssum += __shfl_down(ssum, 16, 64);
    ssum += __shfl_down(ssum,  8, 64); ssum += __shfl_down(ssum,  4, 64);
    ssum += __shfl_down(ssum,  2, 64); ssum += __shfl_down(ssum,  1, 64);
    int wave = tid >> 6, lane = tid & 63;
    if (lane == 0) wred[wave] = ssum;
    __syncthreads();
    if (tid == 0)
        heat[b * kW + wi] = (wred[0] + wred[1] + wred[2] + wred[3]) / (float)span;
}

// --------------------------------------------------------------------------
// K4: coalesced broadcast: out[b,h,w] = qmask ? heat[b,w] : 0
// --------------------------------------------------------------------------
__global__ __launch_bounds__(256)
void out_kernel(const float* __restrict__ heat, const float* __restrict__ qm,
                float* __restrict__ out) {
    int idx = blockIdx.x * 256 + threadIdx.x;
    if (idx >= kB * kH * kW) return;
    int w = idx % kW;
    int b = idx / (kH * kW);
    out[idx] = (qm[b * kW + w] > 0.0f) ? heat[b * kW + w] : 0.0f;
}

extern "C" void kernel_launch(void* const* d_in, const int* in_sizes, int n_in,
                              void* d_out, int out_size, void* d_ws, size_t ws_size,
                              hipStream_t stream) {
    const float* acquired       = (const float*)d_in[0];
    const float* acquiring      = (const float*)d_in[1];
    const float* acquired_mask  = (const float*)d_in[2];
    const float* acquiring_mask = (const float*)d_in[3];
    const float* W1 = (const float*)d_in[4];
    const float* b1 = (const float*)d_in[5];
    const float* W2 = (const float*)d_in[6];
    const float* b2 = (const float*)d_in[7];
    const float* W3 = (const float*)d_in[8];
    const float* b3 = (const float*)d_in[9];
    const float* W4 = (const float*)d_in[10];
    const float* b4 = (const float*)d_in[11];
    float* out = (float*)d_out;

    float* Pa_part = (float*)d_ws;                 // NCH * kN
    float* Pq_part = Pa_part + (size_t)NCH * kN;   // NCH * kN
    float* Pa      = Pq_part + (size_t)NCH * kN;   // kN
    float* Pq      = Pa + kN;                      // kN
    float* heat    = Pq + kN;                      // kB*kW

    proj_kernel<<<dim3(NGRP, NCH, kB), 256, 0, stream>>>(
        acquired, acquiring, acquired_mask, acquiring_mask, W1, Pq_part, Pa_part);
    reduce_kernel<<<(2 * kN + 255) / 256, 256, 0, stream>>>(Pa_part, Pq_part, Pa, Pq);
    pair_kernel<<<dim3(kW, kB), 256, 0, stream>>>(
        Pq, Pa, acquired_mask, acquiring_mask,
        b1, W2, b2, W3, b3, W4, b4, heat);
    int n = kB * kH * kW;
    out_kernel<<<(n + 255) / 256, 256, 0, stream>>>(heat, acquiring_mask, out);
}